// Round 3
// 223.708 us; speedup vs baseline: 1.3368x; 1.3368x over previous
//
#include <hip/hip_runtime.h>

// DynamicFilter: out[b,c,h,w] = sum_p (y[c*9+p] + bias[c*9+p]) * x[b,c,h+dh,w+dw]
//   y[o] = sum_c' x[b,c',h,w] * W[o,c']   (GEMM M=65536, N=2304, K=256, bf16 MFMA)
// B=4, C=256, H=W=128, 9 taps.
// R4: (a) launch_bounds(256,2); (b) A fragments direct from x; (c) Y pitch 20.
// R5: ring-of-3 pipelined B staging (12288-B subtiles), counted vmcnt.
// R6 FIX (R5/R5b NaN root cause): barriers did not drain lgkmcnt, so a wave
//   could pass the phase barrier with previous-phase ds_reads still queued
//   while another wave's global_load_lds DMA overwrote that buffer (every
//   phase stages into the buffer read one phase earlier) -> stale/garbage
//   bf16 -> NaN. Each barrier is now a single asm blob
//   "s_waitcnt vmcnt(N) lgkmcnt(0); s_barrier": lgkm drain gives the
//   __syncthreads-grade LDS ordering, while vmcnt stays COUNTED (lgkmcnt
//   does not track global_load_lds) so the prefetch ring keeps flying.

typedef __attribute__((ext_vector_type(8))) short bf16x8;   // 8 bf16 = 4 VGPRs
typedef __attribute__((ext_vector_type(4))) float f32x4;    // MFMA 16x16 acc

__device__ __forceinline__ unsigned int f2bf(float f) {
    unsigned int u = __float_as_uint(f);
    return (u + 0x7fffu + ((u >> 16) & 1u)) >> 16;   // RNE
}
__device__ __forceinline__ unsigned int pack2(float a, float b) {
    return f2bf(a) | (f2bf(b) << 16);
}

// ---------------------------------------------------------------------------
// Kernel 1: W (2304x256 fp32) -> Wb bf16, k-half-major:
//   Wb[kh][o][16 groups of 8 k], gs = ((gh&7)^(o&7)) | (gh&8)
// ---------------------------------------------------------------------------
__global__ __launch_bounds__(256) void wconv_kernel(const float* __restrict__ W,
                                                    unsigned char* __restrict__ Wb) {
    int idx = blockIdx.x * 256 + threadIdx.x;    // 73728 = 2304 * 32 groups
    int o = idx >> 5, g = idx & 31;
    const float4* src = (const float4*)(W + ((size_t)o << 8) + ((size_t)g << 3));
    float4 v0 = src[0], v1 = src[1];
    uint4 pk;
    pk.x = pack2(v0.x, v0.y); pk.y = pack2(v0.z, v0.w);
    pk.z = pack2(v1.x, v1.y); pk.w = pack2(v1.z, v1.w);
    int kh = g >> 4, gh = g & 15;
    int gs = ((gh & 7) ^ (o & 7)) | (gh & 8);
    size_t dst = (size_t)kh * 589824 + (size_t)o * 256 + ((size_t)gs << 4);
    *(uint4*)(Wb + dst) = pk;
}

// ---------------------------------------------------------------------------
// Kernel 2: fused GEMM + epilogue, ring-3 pipelined staging.
// LDS map: bufs 0,1,2 at 0/12288/24576 (12288 B each); per-wave Y (11520 B,
// pitch 20) at 12288 + wv*11520 (aliases bufs 1,2 only). Total 58368 B.
// Sub-tile j (0..5): kh = j/3, ni-block = (j%3)*3, ring buf = j%3.
// Phase table (stage-target vs read-buffer, never equal in one phase):
//   ph0: stage b1,b2 read b0 | ph1: stage b0 read b1 | ph2: stage b1 read b2
//   ph3: stage b2 read b0 | ph4: stage b0(next sub0) read b1 | ph5: read b2
// ---------------------------------------------------------------------------

// Drain-barrier: wave's LDS ops complete before the HW barrier; vmcnt counted
// (N in flight allowed). Single asm blob = compiler memory fence, no seams.
#define SYNC_VM(N) asm volatile("s_waitcnt vmcnt(" #N ") lgkmcnt(0)\n\ts_barrier" ::: "memory")
#define SYNC_LG    asm volatile("s_waitcnt lgkmcnt(0)\n\ts_barrier" ::: "memory")
#define WAIT_LGKM0 asm volatile("s_waitcnt lgkmcnt(0)" ::: "memory")

// Stage sub-tile J of chunk CH into ring buf J%3. Each wave stages its
// 3072-B quarter with 3 x global_load_lds(16B): per-wave vmcnt += 3.
#define STAGE(CH, J)                                                            \
    do {                                                                        \
        const unsigned char* bs_ = Wb + (size_t)((J) / 3) * 589824              \
            + (size_t)(CH) * 36864 + ((J) % 3) * 12288 + wv * 3072 + (lane << 4); \
        unsigned char* bd_ = smem + ((J) % 3) * 12288 + wv * 3072;              \
        _Pragma("unroll")                                                       \
        for (int c_ = 0; c_ < 3; ++c_)                                          \
            __builtin_amdgcn_global_load_lds(                                   \
                (const __attribute__((address_space(1))) void*)(bs_ + c_ * 1024), \
                (__attribute__((address_space(3))) void*)(bd_ + c_ * 1024), 16, 0, 0); \
    } while (0)

// 24 MFMAs on sub-tile J (3 ni x 2 mi x 4 s): 6 independent acc chains per s.
#define MFMA_SUB(J)                                                             \
    do {                                                                        \
        const int kh_ = (J) / 3, snib_ = ((J) % 3) * 3;                         \
        const unsigned char* bb_ = smem + ((J) % 3) * 12288;                    \
        _Pragma("unroll")                                                       \
        for (int s_ = 0; s_ < 4; ++s_) {                                        \
            const bf16x8 a0_ = afr[(kh_ << 2) + s_];                            \
            const bf16x8 a1_ = afr[8 + (kh_ << 2) + s_];                        \
            const int gb_ = (s_ << 2) + quad;                                   \
            _Pragma("unroll")                                                   \
            for (int ni_ = 0; ni_ < 3; ++ni_) {                                 \
                const bf16x8 bq_ = *(const bf16x8*)(                            \
                    bb_ + (((ni_ << 4) + lrow) << 8) + ((gb_ ^ swz) << 4));     \
                acc[0][snib_ + ni_] = __builtin_amdgcn_mfma_f32_16x16x32_bf16(  \
                    a0_, bq_, acc[0][snib_ + ni_], 0, 0, 0);                    \
                acc[1][snib_ + ni_] = __builtin_amdgcn_mfma_f32_16x16x32_bf16(  \
                    a1_, bq_, acc[1][snib_ + ni_], 0, 0, 0);                    \
            }                                                                   \
        }                                                                       \
    } while (0)

__global__ __launch_bounds__(256, 2) void dfgemm_kernel(
        const unsigned char* __restrict__ Wb, const float* __restrict__ x,
        const float* __restrict__ bias, float* __restrict__ out) {
    __shared__ __align__(16) unsigned char smem[58368];

    const int t = threadIdx.x;
    const int lane = t & 63, wv = t >> 6;
    const int quad = lane >> 4, lrow = lane & 15;
    const int swz = lrow & 7;

    const int b = blockIdx.x >> 7;               // image 0..3
    const int h = blockIdx.x & 127;              // row

    // Warm the pipeline: chunk 0 subs 0,1,2 in flight while afr loads run.
    STAGE(0, 0); STAGE(0, 1); STAGE(0, 2);

    // ---- A fragments direct from x: afr[mi*8+gg][j] = bf16(x[b, gg*32+quad*8+j, h, w]) ----
    bf16x8 afr[16];
    {
        const float* xrow = x + ((size_t)b << 22) + (h << 7);
        #pragma unroll
        for (int mi = 0; mi < 2; ++mi) {
            const int w = (wv << 5) + (mi << 4) + lrow;
            #pragma unroll
            for (int gg = 0; gg < 8; ++gg) {
                const float* p = xrow + ((size_t)((gg << 5) + (quad << 3)) << 14) + w;
                float v[8];
                #pragma unroll
                for (int e = 0; e < 8; ++e) v[e] = p[(size_t)e << 14];
                uint4 pk;
                pk.x = pack2(v[0], v[1]); pk.y = pack2(v[2], v[3]);
                pk.z = pack2(v[4], v[5]); pk.w = pack2(v[6], v[7]);
                afr[(mi << 3) + gg] = *(const bf16x8*)&pk;
            }
        }
    }
    SYNC_VM(0);                        // prologue only: subs 0-2 landed, full drain

    #pragma unroll 1
    for (int chunk = 0; chunk < 16; ++chunk) {
        f32x4 acc[2][9];
        const f32x4 zero = {0.f, 0.f, 0.f, 0.f};
        #pragma unroll
        for (int mi = 0; mi < 2; ++mi)
            #pragma unroll
            for (int ni = 0; ni < 9; ++ni) acc[mi][ni] = zero;

        // Counted-vmcnt bookkeeping (in-order retirement): phase-t sync
        // retires sub-t while the newer stage stays in flight.
        // Loop top: worst case outstanding = [3 sub0 loads][<=8 out-stores];
        // vmcnt(8) retires to <=8 -> sub0 (older) necessarily retired.
        SYNC_VM(8);                            // sub0 ready; all waves past Y reads
        if (chunk) { STAGE(chunk, 1); STAGE(chunk, 2); }   // into bufs 1,2 (ex-Y)
        MFMA_SUB(0);

        SYNC_VM(3);                            // sub1 landed (sub2 may fly)
        STAGE(chunk, 3);                       // buf0 (sub0 readers drained)
        MFMA_SUB(1);

        SYNC_VM(3);                            // sub2 landed (sub3 may fly)
        STAGE(chunk, 4);                       // buf1
        MFMA_SUB(2);

        SYNC_VM(3);                            // sub3 landed
        STAGE(chunk, 5);                       // buf2
        MFMA_SUB(3);

        SYNC_VM(3);                            // sub4 landed
        STAGE((chunk + 1) & 15, 0);            // next chunk sub0 -> buf0 (Y-safe)
        MFMA_SUB(4);

        SYNC_VM(3);                            // sub5 landed (next-sub0 may fly)
        MFMA_SUB(5);

        SYNC_LG;                               // bufs 1,2 reads drained -> Y-safe

        // ---- epilogue: per-wave Y [144 out][20-dword pitch] fp32 (11520 B) ----
        float* Y = (float*)(smem + 12288 + wv * 11520);
        #pragma unroll
        for (int half = 0; half < 2; ++half) {
            #pragma unroll
            for (int ni = 0; ni < 9; ++ni)
                *(f32x4*)(Y + ((ni << 4) + lrow) * 20 + (quad << 2)) = acc[half][ni];
            WAIT_LGKM0;                        // wave-local LDS RAW (no vm drain)

            const int w = (wv << 5) + (half << 4) + lrow;    // this lane's pixel
            #pragma unroll
            for (int it = 0; it < 4; ++it) {
                const int cgl = (it << 2) + quad;            // 0..15
                const int cg = (chunk << 4) + cgl;           // channel 0..255
                const float* yrow = Y + cgl * 180 + lrow;    // (cgl*9+p)*20 + lrow
                const float* bp = bias + cg * 9;
                const float* xc = x + ((size_t)((b << 8) + cg) << 14);
                float sum = 0.f;
                #pragma unroll
                for (int p = 0; p < 9; ++p) {
                    const int hh = h + p / 3 - 1, ww = w + p % 3 - 1;
                    float xv = 0.f;
                    if ((unsigned)hh < 128u && (unsigned)ww < 128u)
                        xv = xc[(hh << 7) + ww];             // fp32 patch
                    sum += (yrow[p * 20] + bp[p]) * xv;
                }
                out[((size_t)((b << 8) + cg) << 14) + (h << 7) + w] = sum;
            }
        }
    }
}

extern "C" void kernel_launch(void* const* d_in, const int* in_sizes, int n_in,
                              void* d_out, int out_size, void* d_ws, size_t ws_size,
                              hipStream_t stream) {
    const float* x    = (const float*)d_in[0];   // 4*256*128*128
    const float* W    = (const float*)d_in[1];   // 2304*256
    const float* bias = (const float*)d_in[2];   // 2304
    float* out = (float*)d_out;

    unsigned char* Wb = (unsigned char*)d_ws;    // 1,179,648 B

    wconv_kernel<<<288, 256, 0, stream>>>(W, Wb);
    dfgemm_kernel<<<512, 256, 0, stream>>>(Wb, x, bias, out);
}